// Round 1
// baseline (1278.165 us; speedup 1.0000x reference)
//
#include <hip/hip_runtime.h>
#include <hip/hip_bf16.h>

#define Bb 4
#define Ss 2048
#define Dd 1024
#define Hh 4096
#define Ee 8
#define Tt (Bb*Ss)

typedef __attribute__((ext_vector_type(8))) short short8;
typedef __attribute__((ext_vector_type(4))) float floatx4;
typedef unsigned short u16;
typedef unsigned int u32;

__device__ __forceinline__ u16 f2bf(float f) {
  union { float f; u32 u; } v; v.f = f;
  return (u16)((v.u + 0x7FFFu + ((v.u >> 16) & 1u)) >> 16);
}

// ---------------- x -> bf16 ----------------
__global__ __launch_bounds__(256) void cvt_x(const float* __restrict__ x, u16* __restrict__ xb) {
  size_t i = ((size_t)blockIdx.x * 256 + threadIdx.x) * 8;
  float4 a = *(const float4*)(x + i);
  float4 b = *(const float4*)(x + i + 4);
  union { u16 us[8]; uint4 v; } o;
  o.us[0] = f2bf(a.x); o.us[1] = f2bf(a.y); o.us[2] = f2bf(a.z); o.us[3] = f2bf(a.w);
  o.us[4] = f2bf(b.x); o.us[5] = f2bf(b.y); o.us[6] = f2bf(b.z); o.us[7] = f2bf(b.w);
  *(uint4*)(xb + i) = o.v;
}

// ------- [E][R][C] fp32 -> [E][C][R] bf16 (transpose + convert) -------
__global__ __launch_bounds__(256) void tconv(const float* __restrict__ src, u16* __restrict__ dst,
                                             int R, int C) {
  __shared__ float tile[64][65];
  int e = blockIdx.z;
  int r0 = blockIdx.y * 64, c0 = blockIdx.x * 64;
  int tx = threadIdx.x & 63, ty = threadIdx.x >> 6;
  const float* s = src + (size_t)e * R * C;
  u16* d = dst + (size_t)e * R * C;
#pragma unroll
  for (int i = 0; i < 16; i++) {
    int r = i * 4 + ty;
    tile[r][tx] = s[(size_t)(r0 + r) * C + c0 + tx];
  }
  __syncthreads();
#pragma unroll
  for (int i = 0; i < 16; i++) {
    int c = i * 4 + ty;
    d[(size_t)(c0 + c) * R + r0 + tx] = f2bf(tile[tx][c]);
  }
}

// ---------------- gating: gates, top-2, softmax, routing lists ----------------
__global__ __launch_bounds__(256) void gate_kernel(const float* __restrict__ x,
                                                   const float* __restrict__ gw,
                                                   const float* __restrict__ gb,
                                                   int* __restrict__ counts,
                                                   int* __restrict__ tokL,
                                                   int* __restrict__ pairL,
                                                   float* __restrict__ wtL) {
  __shared__ float gwl[Dd * Ee];  // 32 KB
  for (int i = threadIdx.x; i < Dd * Ee; i += 256) gwl[i] = gw[i];
  __syncthreads();
  int wid = threadIdx.x >> 6, lane = threadIdx.x & 63;
  int t = blockIdx.x * 4 + wid;
  const float* xr = x + (size_t)t * Dd;
  double acc[Ee];
#pragma unroll
  for (int e = 0; e < Ee; e++) acc[e] = 0.0;
  for (int i = 0; i < Dd / 64; i++) {
    int d = lane + i * 64;
    float xv = xr[d];
#pragma unroll
    for (int e = 0; e < Ee; e++) acc[e] += (double)xv * (double)gwl[d * Ee + e];
  }
#pragma unroll
  for (int off = 32; off > 0; off >>= 1)
#pragma unroll
    for (int e = 0; e < Ee; e++) acc[e] += __shfl_down(acc[e], off);
  if (lane == 0) {
    float s[Ee];
#pragma unroll
    for (int e = 0; e < Ee; e++) s[e] = (float)acc[e] + gb[e];
    int i0 = 0;
#pragma unroll
    for (int e = 1; e < Ee; e++) if (s[e] > s[i0]) i0 = e;
    int i1 = (i0 == 0) ? 1 : 0;
#pragma unroll
    for (int e = 0; e < Ee; e++) if (e != i0 && s[e] > s[i1]) i1 = e;
    float ex = expf(s[i1] - s[i0]);
    float g0 = 1.0f / (1.0f + ex);
    float g1 = ex / (1.0f + ex);
    int p0 = atomicAdd(&counts[i0], 1);
    tokL[i0 * Tt + p0] = t; pairL[i0 * Tt + p0] = t * 2;     wtL[i0 * Tt + p0] = g0;
    int p1 = atomicAdd(&counts[i1], 1);
    tokL[i1 * Tt + p1] = t; pairL[i1 * Tt + p1] = t * 2 + 1; wtL[i1 * Tt + p1] = g1;
  }
}

// ---------------- GEMM1: h = gelu(X[tok] @ w1[e] + b1[e]) ----------------
__global__ __launch_bounds__(256) void gemm1(const u16* __restrict__ xb,
                                             const u16* __restrict__ w1t,  // [E][H][D] bf16
                                             const float* __restrict__ b1,
                                             const int* __restrict__ counts,
                                             const int* __restrict__ tokL,
                                             const int* __restrict__ pairL,
                                             u16* __restrict__ h) {
  int e = blockIdx.z;
  int cnt = counts[e];
  int m0 = blockIdx.y * 128;
  if (m0 >= cnt) return;
  int rows = cnt - m0; if (rows > 128) rows = 128;
  int n0 = blockIdx.x * 128;

  __shared__ __align__(16) u16 As[128 * 40];
  __shared__ __align__(16) u16 Bs[128 * 40];
  __shared__ int ltok[128];
  __shared__ int lpair[128];

  int tid = threadIdx.x;
  if (tid < 128) {
    int ok = tid < rows;
    ltok[tid]  = ok ? tokL[e * Tt + m0 + tid] : 0;
    lpair[tid] = ok ? pairL[e * Tt + m0 + tid] : 0;
  }
  __syncthreads();

  floatx4 zero4 = {0.f, 0.f, 0.f, 0.f};
  floatx4 acc[4][4];
#pragma unroll
  for (int i = 0; i < 4; i++)
#pragma unroll
    for (int j = 0; j < 4; j++) acc[i][j] = zero4;

  int wave = tid >> 6, lane = tid & 63;
  int wr = wave >> 1, wc = wave & 1;
  int lm = lane & 15, lq = lane >> 4;

  for (int k0 = 0; k0 < Dd; k0 += 32) {
#pragma unroll
    for (int c = tid; c < 512; c += 256) {
      int row = c >> 2, q = c & 3;
      uint4 av = make_uint4(0, 0, 0, 0);
      if (row < rows) av = *(const uint4*)(xb + (size_t)ltok[row] * Dd + k0 + q * 8);
      *(uint4*)(As + row * 40 + q * 8) = av;
      *(uint4*)(Bs + row * 40 + q * 8) =
          *(const uint4*)(w1t + ((size_t)e * Hh + n0 + row) * Dd + k0 + q * 8);
    }
    __syncthreads();
    short8 a[4], b[4];
#pragma unroll
    for (int i = 0; i < 4; i++) a[i] = *(const short8*)(As + (wr * 64 + i * 16 + lm) * 40 + lq * 8);
#pragma unroll
    for (int j = 0; j < 4; j++) b[j] = *(const short8*)(Bs + (wc * 64 + j * 16 + lm) * 40 + lq * 8);
#pragma unroll
    for (int i = 0; i < 4; i++)
#pragma unroll
      for (int j = 0; j < 4; j++)
        acc[i][j] = __builtin_amdgcn_mfma_f32_16x16x32_bf16(a[i], b[j], acc[i][j], 0, 0, 0);
    __syncthreads();
  }

#pragma unroll
  for (int i = 0; i < 4; i++) {
    int rbase = wr * 64 + i * 16 + lq * 4;
#pragma unroll
    for (int r = 0; r < 4; r++) {
      int row = rbase + r;
      if (row < rows) {
        int p = lpair[row];
#pragma unroll
        for (int j = 0; j < 4; j++) {
          int col = n0 + wc * 64 + j * 16 + lm;
          float v = acc[i][j][r] + b1[e * Hh + col];
          v = 0.5f * v * (1.0f + erff(v * 0.70710678118f));
          h[(size_t)p * Hh + col] = f2bf(v);
        }
      }
    }
  }
}

// ---------------- GEMM2: out[tok] += wt * (h @ w2[e] + b2[e]) ----------------
__global__ __launch_bounds__(256) void gemm2(const u16* __restrict__ h,
                                             const u16* __restrict__ w2t,  // [E][D][H] bf16
                                             const float* __restrict__ b2,
                                             const int* __restrict__ counts,
                                             const int* __restrict__ tokL,
                                             const int* __restrict__ pairL,
                                             const float* __restrict__ wtL,
                                             float* __restrict__ out) {
  int e = blockIdx.z;
  int cnt = counts[e];
  int m0 = blockIdx.y * 128;
  if (m0 >= cnt) return;
  int rows = cnt - m0; if (rows > 128) rows = 128;
  int n0 = blockIdx.x * 128;

  __shared__ __align__(16) u16 As[128 * 40];
  __shared__ __align__(16) u16 Bs[128 * 40];
  __shared__ int ltok[128];
  __shared__ int lpair[128];
  __shared__ float lwt[128];

  int tid = threadIdx.x;
  if (tid < 128) {
    int ok = tid < rows;
    ltok[tid]  = ok ? tokL[e * Tt + m0 + tid] : 0;
    lpair[tid] = ok ? pairL[e * Tt + m0 + tid] : 0;
    lwt[tid]   = ok ? wtL[e * Tt + m0 + tid] : 0.f;
  }
  __syncthreads();

  floatx4 zero4 = {0.f, 0.f, 0.f, 0.f};
  floatx4 acc[4][4];
#pragma unroll
  for (int i = 0; i < 4; i++)
#pragma unroll
    for (int j = 0; j < 4; j++) acc[i][j] = zero4;

  int wave = tid >> 6, lane = tid & 63;
  int wr = wave >> 1, wc = wave & 1;
  int lm = lane & 15, lq = lane >> 4;

  for (int k0 = 0; k0 < Hh; k0 += 32) {
#pragma unroll
    for (int c = tid; c < 512; c += 256) {
      int row = c >> 2, q = c & 3;
      uint4 av = make_uint4(0, 0, 0, 0);
      if (row < rows) av = *(const uint4*)(h + (size_t)lpair[row] * Hh + k0 + q * 8);
      *(uint4*)(As + row * 40 + q * 8) = av;
      *(uint4*)(Bs + row * 40 + q * 8) =
          *(const uint4*)(w2t + ((size_t)e * Dd + n0 + row) * Hh + k0 + q * 8);
    }
    __syncthreads();
    short8 a[4], b[4];
#pragma unroll
    for (int i = 0; i < 4; i++) a[i] = *(const short8*)(As + (wr * 64 + i * 16 + lm) * 40 + lq * 8);
#pragma unroll
    for (int j = 0; j < 4; j++) b[j] = *(const short8*)(Bs + (wc * 64 + j * 16 + lm) * 40 + lq * 8);
#pragma unroll
    for (int i = 0; i < 4; i++)
#pragma unroll
      for (int j = 0; j < 4; j++)
        acc[i][j] = __builtin_amdgcn_mfma_f32_16x16x32_bf16(a[i], b[j], acc[i][j], 0, 0, 0);
    __syncthreads();
  }

#pragma unroll
  for (int i = 0; i < 4; i++) {
    int rbase = wr * 64 + i * 16 + lq * 4;
#pragma unroll
    for (int r = 0; r < 4; r++) {
      int row = rbase + r;
      if (row < rows) {
        int t = ltok[row];
        float w = lwt[row];
#pragma unroll
        for (int j = 0; j < 4; j++) {
          int col = n0 + wc * 64 + j * 16 + lm;
          float v = (acc[i][j][r] + b2[e * Dd + col]) * w;
          atomicAdd(out + (size_t)t * Dd + col, v);
        }
      }
    }
  }
}

extern "C" void kernel_launch(void* const* d_in, const int* in_sizes, int n_in,
                              void* d_out, int out_size, void* d_ws, size_t ws_size,
                              hipStream_t stream) {
  const float* x      = (const float*)d_in[0];
  const float* gate_w = (const float*)d_in[1];
  const float* gate_b = (const float*)d_in[2];
  const float* w1     = (const float*)d_in[3];
  const float* b1     = (const float*)d_in[4];
  const float* w2     = (const float*)d_in[5];
  const float* b2     = (const float*)d_in[6];
  float* out = (float*)d_out;

  char* ws = (char*)d_ws;
  size_t off = 0;
  int* counts = (int*)(ws + off); off += 256;
  int* tokL   = (int*)(ws + off); off += (size_t)Ee * Tt * 4;
  int* pairL  = (int*)(ws + off); off += (size_t)Ee * Tt * 4;
  float* wtL  = (float*)(ws + off); off += (size_t)Ee * Tt * 4;
  u16* xb     = (u16*)(ws + off); off += (size_t)Tt * Dd * 2;
  u16* w1t    = (u16*)(ws + off); off += (size_t)Ee * Hh * Dd * 2;
  u16* w2t    = (u16*)(ws + off); off += (size_t)Ee * Dd * Hh * 2;
  u16* hbuf   = (u16*)(ws + off); off += (size_t)Tt * 2 * Hh * 2;

  hipMemsetAsync(counts, 0, 256, stream);
  hipMemsetAsync(out, 0, (size_t)Tt * Dd * 4, stream);

  cvt_x<<<(Tt * Dd) / (256 * 8), 256, 0, stream>>>(x, xb);
  tconv<<<dim3(Hh / 64, Dd / 64, Ee), 256, 0, stream>>>(w1, w1t, Dd, Hh);  // w1 [E][D][H] -> [E][H][D]
  tconv<<<dim3(Dd / 64, Hh / 64, Ee), 256, 0, stream>>>(w2, w2t, Hh, Dd);  // w2 [E][H][D] -> [E][D][H]
  gate_kernel<<<Tt / 4, 256, 0, stream>>>(x, gate_w, gate_b, counts, tokL, pairL, wtL);
  gemm1<<<dim3(Hh / 128, Tt / 128, Ee), 256, 0, stream>>>(xb, w1t, b1, counts, tokL, pairL, hbuf);
  gemm2<<<dim3(Dd / 128, Tt / 128, Ee), 256, 0, stream>>>(hbuf, w2t, b2, counts, tokL, pairL, wtL, out);
}

// Round 2
// 1119.584 us; speedup vs baseline: 1.1416x; 1.1416x over previous
//
#include <hip/hip_runtime.h>
#include <hip/hip_bf16.h>

#define Bb 4
#define Ss 2048
#define Dd 1024
#define Hh 4096
#define Ee 8
#define Tt (Bb*Ss)

typedef __attribute__((ext_vector_type(8))) short short8;
typedef __attribute__((ext_vector_type(4))) float floatx4;
typedef unsigned short u16;
typedef unsigned int u32;

__device__ __forceinline__ u16 f2bf(float f) {
  union { float f; u32 u; } v; v.f = f;
  return (u16)((v.u + 0x7FFFu + ((v.u >> 16) & 1u)) >> 16);
}

// async global->LDS, 16 B per lane; LDS dest = wave-uniform base + lane*16
__device__ __forceinline__ void async16(const u16* g, u16* l) {
  __builtin_amdgcn_global_load_lds(
      (const __attribute__((address_space(1))) unsigned int*)g,
      (__attribute__((address_space(3))) unsigned int*)l, 16, 0, 0);
}

// ---------------- x -> bf16 ----------------
__global__ __launch_bounds__(256) void cvt_x(const float* __restrict__ x, u16* __restrict__ xb) {
  size_t i = ((size_t)blockIdx.x * 256 + threadIdx.x) * 8;
  float4 a = *(const float4*)(x + i);
  float4 b = *(const float4*)(x + i + 4);
  union { u16 us[8]; uint4 v; } o;
  o.us[0] = f2bf(a.x); o.us[1] = f2bf(a.y); o.us[2] = f2bf(a.z); o.us[3] = f2bf(a.w);
  o.us[4] = f2bf(b.x); o.us[5] = f2bf(b.y); o.us[6] = f2bf(b.z); o.us[7] = f2bf(b.w);
  *(uint4*)(xb + i) = o.v;
}

// ------- [E][R][C] fp32 -> [E][C][R] bf16 (transpose + convert) -------
__global__ __launch_bounds__(256) void tconv(const float* __restrict__ src, u16* __restrict__ dst,
                                             int R, int C) {
  __shared__ float tile[64][65];
  int e = blockIdx.z;
  int r0 = blockIdx.y * 64, c0 = blockIdx.x * 64;
  int tx = threadIdx.x & 63, ty = threadIdx.x >> 6;
  const float* s = src + (size_t)e * R * C;
  u16* d = dst + (size_t)e * R * C;
#pragma unroll
  for (int i = 0; i < 16; i++) {
    int r = i * 4 + ty;
    tile[r][tx] = s[(size_t)(r0 + r) * C + c0 + tx];
  }
  __syncthreads();
#pragma unroll
  for (int i = 0; i < 16; i++) {
    int c = i * 4 + ty;
    d[(size_t)(c0 + c) * R + r0 + tx] = f2bf(tile[tx][c]);
  }
}

// ---------------- gating ----------------
__global__ __launch_bounds__(256) void gate_kernel(const float* __restrict__ x,
                                                   const float* __restrict__ gw,
                                                   const float* __restrict__ gb,
                                                   int* __restrict__ counts,
                                                   int* __restrict__ tokL,
                                                   int* __restrict__ pairL,
                                                   float* __restrict__ wtL) {
  __shared__ float gwl[Dd * Ee];
  for (int i = threadIdx.x; i < Dd * Ee; i += 256) gwl[i] = gw[i];
  __syncthreads();
  int wid = threadIdx.x >> 6, lane = threadIdx.x & 63;
  int t = blockIdx.x * 4 + wid;
  const float* xr = x + (size_t)t * Dd;
  double acc[Ee];
#pragma unroll
  for (int e = 0; e < Ee; e++) acc[e] = 0.0;
  for (int i = 0; i < Dd / 64; i++) {
    int d = lane + i * 64;
    float xv = xr[d];
#pragma unroll
    for (int e = 0; e < Ee; e++) acc[e] += (double)xv * (double)gwl[d * Ee + e];
  }
#pragma unroll
  for (int off = 32; off > 0; off >>= 1)
#pragma unroll
    for (int e = 0; e < Ee; e++) acc[e] += __shfl_down(acc[e], off);
  if (lane == 0) {
    float s[Ee];
#pragma unroll
    for (int e = 0; e < Ee; e++) s[e] = (float)acc[e] + gb[e];
    int i0 = 0;
#pragma unroll
    for (int e = 1; e < Ee; e++) if (s[e] > s[i0]) i0 = e;
    int i1 = (i0 == 0) ? 1 : 0;
#pragma unroll
    for (int e = 0; e < Ee; e++) if (e != i0 && s[e] > s[i1]) i1 = e;
    float ex = expf(s[i1] - s[i0]);
    float g0 = 1.0f / (1.0f + ex);
    float g1 = ex / (1.0f + ex);
    int p0 = atomicAdd(&counts[i0], 1);
    tokL[i0 * Tt + p0] = t; pairL[i0 * Tt + p0] = t * 2;     wtL[i0 * Tt + p0] = g0;
    int p1 = atomicAdd(&counts[i1], 1);
    tokL[i1 * Tt + p1] = t; pairL[i1 * Tt + p1] = t * 2 + 1; wtL[i1 * Tt + p1] = g1;
  }
}

// ---------------- GEMM1: h = gelu(X[tok] @ w1[e] + b1[e]) ----------------
// grid (32, 64, E); XCD-swizzled (m,n) remap. BM=BN=128, BK=32.
__global__ __launch_bounds__(256) void gemm1(const u16* __restrict__ xb,
                                             const u16* __restrict__ w1t,  // [E][H][D] bf16
                                             const float* __restrict__ b1,
                                             const int* __restrict__ counts,
                                             const int* __restrict__ tokL,
                                             const int* __restrict__ pairL,
                                             u16* __restrict__ h) {
  const int NT = 32;
  int e = blockIdx.z;
  int cnt = counts[e];
  int flat = blockIdx.x + NT * blockIdx.y;
  int x8 = flat & 7, j = flat >> 3;
  int n_t = j % NT;
  int m_t = (j / NT) * 8 + x8;
  int m0 = m_t * 128;
  if (m0 >= cnt) return;
  int rows = cnt - m0; if (rows > 128) rows = 128;
  int n0 = n_t * 128;

  __shared__ __align__(16) u16 As[128 * 32];
  __shared__ __align__(16) u16 Bs[128 * 32];
  __shared__ int ltok[128];
  __shared__ int lpair[128];

  int tid = threadIdx.x;
  if (tid < 128) {
    int ok = tid < rows;
    ltok[tid]  = ok ? tokL[e * Tt + m0 + tid] : tokL[e * Tt + m0];
    lpair[tid] = ok ? pairL[e * Tt + m0 + tid] : 0;
  }
  __syncthreads();

  int wv = tid >> 6, ln = tid & 63;
  int half = wv & 1;
  const u16* gp[4];
  u16* ldst[4];
  if (wv < 2) {
#pragma unroll
    for (int q = 0; q < 4; q++) {
      int r = half * 64 + q * 16 + (ln >> 2);
      int c = (ln & 3) ^ ((r >> 1) & 3);
      gp[q] = xb + (size_t)ltok[r] * Dd + c * 8;
      ldst[q] = As + (half * 64 + q * 16) * 32;
    }
  } else {
#pragma unroll
    for (int q = 0; q < 4; q++) {
      int r = half * 64 + q * 16 + (ln >> 2);
      int c = (ln & 3) ^ ((r >> 1) & 3);
      gp[q] = w1t + ((size_t)e * Hh + n0 + r) * Dd + c * 8;
      ldst[q] = Bs + (half * 64 + q * 16) * 32;
    }
  }

  floatx4 zero4 = {0.f, 0.f, 0.f, 0.f};
  floatx4 acc[4][4];
#pragma unroll
  for (int i = 0; i < 4; i++)
#pragma unroll
    for (int jj = 0; jj < 4; jj++) acc[i][jj] = zero4;

  int wr = wv >> 1, wc = wv & 1;
  int lm = ln & 15, lq = ln >> 4;

  for (int k0 = 0; k0 < Dd; k0 += 32) {
#pragma unroll
    for (int q = 0; q < 4; q++) async16(gp[q], ldst[q]);
#pragma unroll
    for (int q = 0; q < 4; q++) gp[q] += 32;
    __syncthreads();
    short8 a[4], b[4];
#pragma unroll
    for (int i = 0; i < 4; i++) {
      int row = wr * 64 + i * 16 + lm;
      int p = lq ^ ((row >> 1) & 3);
      a[i] = *(const short8*)(As + row * 32 + p * 8);
    }
#pragma unroll
    for (int jj = 0; jj < 4; jj++) {
      int row = wc * 64 + jj * 16 + lm;
      int p = lq ^ ((row >> 1) & 3);
      b[jj] = *(const short8*)(Bs + row * 32 + p * 8);
    }
#pragma unroll
    for (int i = 0; i < 4; i++)
#pragma unroll
      for (int jj = 0; jj < 4; jj++)
        acc[i][jj] = __builtin_amdgcn_mfma_f32_16x16x32_bf16(a[i], b[jj], acc[i][jj], 0, 0, 0);
    __syncthreads();
  }

#pragma unroll
  for (int i = 0; i < 4; i++) {
    int rbase = wr * 64 + i * 16 + lq * 4;
#pragma unroll
    for (int r = 0; r < 4; r++) {
      int row = rbase + r;
      if (row < rows) {
        int p = lpair[row];
#pragma unroll
        for (int jj = 0; jj < 4; jj++) {
          int col = n0 + wc * 64 + jj * 16 + lm;
          float v = acc[i][jj][r] + b1[e * Hh + col];
          v = 0.5f * v * (1.0f + erff(v * 0.70710678118f));
          h[(size_t)p * Hh + col] = f2bf(v);
        }
      }
    }
  }
}

// ---------------- GEMM2: out[tok] += wt * (h @ w2[e] + b2[e]) ----------------
// grid (8, 64, E)
__global__ __launch_bounds__(256) void gemm2(const u16* __restrict__ h,
                                             const u16* __restrict__ w2t,  // [E][D][H] bf16
                                             const float* __restrict__ b2,
                                             const int* __restrict__ counts,
                                             const int* __restrict__ tokL,
                                             const int* __restrict__ pairL,
                                             const float* __restrict__ wtL,
                                             float* __restrict__ out) {
  const int NT = 8;
  int e = blockIdx.z;
  int cnt = counts[e];
  int flat = blockIdx.x + NT * blockIdx.y;
  int x8 = flat & 7, j = flat >> 3;
  int n_t = j % NT;
  int m_t = (j / NT) * 8 + x8;
  int m0 = m_t * 128;
  if (m0 >= cnt) return;
  int rows = cnt - m0; if (rows > 128) rows = 128;
  int n0 = n_t * 128;

  __shared__ __align__(16) u16 As[128 * 32];
  __shared__ __align__(16) u16 Bs[128 * 32];
  __shared__ int ltok[128];
  __shared__ int lpair[128];
  __shared__ float lwt[128];

  int tid = threadIdx.x;
  if (tid < 128) {
    int ok = tid < rows;
    ltok[tid]  = ok ? tokL[e * Tt + m0 + tid] : 0;
    lpair[tid] = ok ? pairL[e * Tt + m0 + tid] : pairL[e * Tt + m0];
    lwt[tid]   = ok ? wtL[e * Tt + m0 + tid] : 0.f;
  }
  __syncthreads();

  int wv = tid >> 6, ln = tid & 63;
  int half = wv & 1;
  const u16* gp[4];
  u16* ldst[4];
  if (wv < 2) {
#pragma unroll
    for (int q = 0; q < 4; q++) {
      int r = half * 64 + q * 16 + (ln >> 2);
      int c = (ln & 3) ^ ((r >> 1) & 3);
      gp[q] = h + (size_t)lpair[r] * Hh + c * 8;
      ldst[q] = As + (half * 64 + q * 16) * 32;
    }
  } else {
#pragma unroll
    for (int q = 0; q < 4; q++) {
      int r = half * 64 + q * 16 + (ln >> 2);
      int c = (ln & 3) ^ ((r >> 1) & 3);
      gp[q] = w2t + ((size_t)e * Dd + n0 + r) * Hh + c * 8;
      ldst[q] = Bs + (half * 64 + q * 16) * 32;
    }
  }

  floatx4 zero4 = {0.f, 0.f, 0.f, 0.f};
  floatx4 acc[4][4];
#pragma unroll
  for (int i = 0; i < 4; i++)
#pragma unroll
    for (int jj = 0; jj < 4; jj++) acc[i][jj] = zero4;

  int wr = wv >> 1, wc = wv & 1;
  int lm = ln & 15, lq = ln >> 4;

  for (int k0 = 0; k0 < Hh; k0 += 32) {
#pragma unroll
    for (int q = 0; q < 4; q++) async16(gp[q], ldst[q]);
#pragma unroll
    for (int q = 0; q < 4; q++) gp[q] += 32;
    __syncthreads();
    short8 a[4], b[4];
#pragma unroll
    for (int i = 0; i < 4; i++) {
      int row = wr * 64 + i * 16 + lm;
      int p = lq ^ ((row >> 1) & 3);
      a[i] = *(const short8*)(As + row * 32 + p * 8);
    }
#pragma unroll
    for (int jj = 0; jj < 4; jj++) {
      int row = wc * 64 + jj * 16 + lm;
      int p = lq ^ ((row >> 1) & 3);
      b[jj] = *(const short8*)(Bs + row * 32 + p * 8);
    }
#pragma unroll
    for (int i = 0; i < 4; i++)
#pragma unroll
      for (int jj = 0; jj < 4; jj++)
        acc[i][jj] = __builtin_amdgcn_mfma_f32_16x16x32_bf16(a[i], b[jj], acc[i][jj], 0, 0, 0);
    __syncthreads();
  }

#pragma unroll
  for (int i = 0; i < 4; i++) {
    int rbase = wr * 64 + i * 16 + lq * 4;
#pragma unroll
    for (int r = 0; r < 4; r++) {
      int row = rbase + r;
      if (row < rows) {
        int t = ltok[row];
        float w = lwt[row];
#pragma unroll
        for (int jj = 0; jj < 4; jj++) {
          int col = n0 + wc * 64 + jj * 16 + lm;
          float v = (acc[i][jj][r] + b2[e * Dd + col]) * w;
          atomicAdd(out + (size_t)t * Dd + col, v);
        }
      }
    }
  }
}

extern "C" void kernel_launch(void* const* d_in, const int* in_sizes, int n_in,
                              void* d_out, int out_size, void* d_ws, size_t ws_size,
                              hipStream_t stream) {
  const float* x      = (const float*)d_in[0];
  const float* gate_w = (const float*)d_in[1];
  const float* gate_b = (const float*)d_in[2];
  const float* w1     = (const float*)d_in[3];
  const float* b1     = (const float*)d_in[4];
  const float* w2     = (const float*)d_in[5];
  const float* b2     = (const float*)d_in[6];
  float* out = (float*)d_out;

  char* ws = (char*)d_ws;
  size_t off = 0;
  int* counts = (int*)(ws + off); off += 256;
  int* tokL   = (int*)(ws + off); off += (size_t)Ee * Tt * 4;
  int* pairL  = (int*)(ws + off); off += (size_t)Ee * Tt * 4;
  float* wtL  = (float*)(ws + off); off += (size_t)Ee * Tt * 4;
  u16* xb     = (u16*)(ws + off); off += (size_t)Tt * Dd * 2;
  u16* w1t    = (u16*)(ws + off); off += (size_t)Ee * Hh * Dd * 2;
  u16* w2t    = (u16*)(ws + off); off += (size_t)Ee * Dd * Hh * 2;
  u16* hbuf   = (u16*)(ws + off); off += (size_t)Tt * 2 * Hh * 2;

  hipMemsetAsync(counts, 0, 256, stream);
  hipMemsetAsync(out, 0, (size_t)Tt * Dd * 4, stream);

  cvt_x<<<(Tt * Dd) / (256 * 8), 256, 0, stream>>>(x, xb);
  tconv<<<dim3(Hh / 64, Dd / 64, Ee), 256, 0, stream>>>(w1, w1t, Dd, Hh);
  tconv<<<dim3(Dd / 64, Hh / 64, Ee), 256, 0, stream>>>(w2, w2t, Hh, Dd);
  gate_kernel<<<Tt / 4, 256, 0, stream>>>(x, gate_w, gate_b, counts, tokL, pairL, wtL);
  gemm1<<<dim3(32, 64, Ee), 256, 0, stream>>>(xb, w1t, b1, counts, tokL, pairL, hbuf);
  gemm2<<<dim3(8, 64, Ee), 256, 0, stream>>>(hbuf, w2t, b2, counts, tokL, pairL, wtL, out);
}

// Round 3
// 1109.576 us; speedup vs baseline: 1.1519x; 1.0090x over previous
//
#include <hip/hip_runtime.h>
#include <hip/hip_bf16.h>

#define Bb 4
#define Ss 2048
#define Dd 1024
#define Hh 4096
#define Ee 8
#define Tt (Bb*Ss)

typedef __attribute__((ext_vector_type(8))) short short8;
typedef __attribute__((ext_vector_type(4))) float floatx4;
typedef unsigned short u16;
typedef unsigned int u32;

__device__ __forceinline__ u16 f2bf(float f) {
  union { float f; u32 u; } v; v.f = f;
  return (u16)((v.u + 0x7FFFu + ((v.u >> 16) & 1u)) >> 16);
}

// async global->LDS, 16 B per lane; LDS dest = wave-uniform base + lane*16
__device__ __forceinline__ void async16(const u16* g, u16* l) {
  __builtin_amdgcn_global_load_lds(
      (const __attribute__((address_space(1))) unsigned int*)g,
      (__attribute__((address_space(3))) unsigned int*)l, 16, 0, 0);
}

// ---------------- x -> bf16 ----------------
__global__ __launch_bounds__(256) void cvt_x(const float* __restrict__ x, u16* __restrict__ xb) {
  size_t i = ((size_t)blockIdx.x * 256 + threadIdx.x) * 8;
  float4 a = *(const float4*)(x + i);
  float4 b = *(const float4*)(x + i + 4);
  union { u16 us[8]; uint4 v; } o;
  o.us[0] = f2bf(a.x); o.us[1] = f2bf(a.y); o.us[2] = f2bf(a.z); o.us[3] = f2bf(a.w);
  o.us[4] = f2bf(b.x); o.us[5] = f2bf(b.y); o.us[6] = f2bf(b.z); o.us[7] = f2bf(b.w);
  *(uint4*)(xb + i) = o.v;
}

// ------- [E][R][C] fp32 -> [E][C][R] bf16 (transpose + convert) -------
__global__ __launch_bounds__(256) void tconv(const float* __restrict__ src, u16* __restrict__ dst,
                                             int R, int C) {
  __shared__ float tile[64][65];
  int e = blockIdx.z;
  int r0 = blockIdx.y * 64, c0 = blockIdx.x * 64;
  int tx = threadIdx.x & 63, ty = threadIdx.x >> 6;
  const float* s = src + (size_t)e * R * C;
  u16* d = dst + (size_t)e * R * C;
#pragma unroll
  for (int i = 0; i < 16; i++) {
    int r = i * 4 + ty;
    tile[r][tx] = s[(size_t)(r0 + r) * C + c0 + tx];
  }
  __syncthreads();
#pragma unroll
  for (int i = 0; i < 16; i++) {
    int c = i * 4 + ty;
    d[(size_t)(c0 + c) * R + r0 + tx] = f2bf(tile[tx][c]);
  }
}

// ---------------- gating ----------------
__global__ __launch_bounds__(256) void gate_kernel(const float* __restrict__ x,
                                                   const float* __restrict__ gw,
                                                   const float* __restrict__ gb,
                                                   int* __restrict__ counts,
                                                   int* __restrict__ tokL,
                                                   int* __restrict__ pairL,
                                                   float* __restrict__ wtL) {
  __shared__ float gwl[Dd * Ee];
  for (int i = threadIdx.x; i < Dd * Ee; i += 256) gwl[i] = gw[i];
  __syncthreads();
  int wid = threadIdx.x >> 6, lane = threadIdx.x & 63;
  int t = blockIdx.x * 4 + wid;
  const float* xr = x + (size_t)t * Dd;
  double acc[Ee];
#pragma unroll
  for (int e = 0; e < Ee; e++) acc[e] = 0.0;
  for (int i = 0; i < Dd / 64; i++) {
    int d = lane + i * 64;
    float xv = xr[d];
#pragma unroll
    for (int e = 0; e < Ee; e++) acc[e] += (double)xv * (double)gwl[d * Ee + e];
  }
#pragma unroll
  for (int off = 32; off > 0; off >>= 1)
#pragma unroll
    for (int e = 0; e < Ee; e++) acc[e] += __shfl_down(acc[e], off);
  if (lane == 0) {
    float s[Ee];
#pragma unroll
    for (int e = 0; e < Ee; e++) s[e] = (float)acc[e] + gb[e];
    int i0 = 0;
#pragma unroll
    for (int e = 1; e < Ee; e++) if (s[e] > s[i0]) i0 = e;
    int i1 = (i0 == 0) ? 1 : 0;
#pragma unroll
    for (int e = 0; e < Ee; e++) if (e != i0 && s[e] > s[i1]) i1 = e;
    float ex = expf(s[i1] - s[i0]);
    float g0 = 1.0f / (1.0f + ex);
    float g1 = ex / (1.0f + ex);
    int p0 = atomicAdd(&counts[i0], 1);
    tokL[i0 * Tt + p0] = t; pairL[i0 * Tt + p0] = t * 2;     wtL[i0 * Tt + p0] = g0;
    int p1 = atomicAdd(&counts[i1], 1);
    tokL[i1 * Tt + p1] = t; pairL[i1 * Tt + p1] = t * 2 + 1; wtL[i1 * Tt + p1] = g1;
  }
}

// ---------------- GEMM1: h = gelu(X[tok] @ w1[e] + b1[e]) ----------------
// grid (32, 64, E); XCD-swizzled (m,n); BM=BN=128, BK=32, 2-stage dbuf.
__global__ __launch_bounds__(256) void gemm1(const u16* __restrict__ xb,
                                             const u16* __restrict__ w1t,  // [E][H][D] bf16
                                             const float* __restrict__ b1,
                                             const int* __restrict__ counts,
                                             const int* __restrict__ tokL,
                                             const int* __restrict__ pairL,
                                             u16* __restrict__ h) {
  const int NT = 32;
  int e = blockIdx.z;
  int cnt = counts[e];
  int flat = blockIdx.x + NT * blockIdx.y;
  int x8 = flat & 7, j = flat >> 3;
  int n_t = j % NT;
  int m_t = (j / NT) * 8 + x8;
  int m0 = m_t * 128;
  if (m0 >= cnt) return;
  int rows = cnt - m0; if (rows > 128) rows = 128;
  int n0 = n_t * 128;

  __shared__ __align__(16) u16 As[2 * 128 * 32];
  __shared__ __align__(16) u16 Bs[2 * 128 * 32];
  __shared__ int ltok[128];
  __shared__ int lpair[128];

  int tid = threadIdx.x;
  if (tid < 128) {
    int ok = tid < rows;
    ltok[tid]  = ok ? tokL[e * Tt + m0 + tid] : tokL[e * Tt + m0];
    lpair[tid] = ok ? pairL[e * Tt + m0 + tid] : 0;
  }
  __syncthreads();

  int wv = tid >> 6, ln = tid & 63;
  int half = wv & 1;
  const u16* gp[4];
  u16* ldst[4];
  if (wv < 2) {
#pragma unroll
    for (int q = 0; q < 4; q++) {
      int r = half * 64 + q * 16 + (ln >> 2);
      int c = (ln & 3) ^ ((r >> 1) & 3);
      gp[q] = xb + (size_t)ltok[r] * Dd + c * 8;
      ldst[q] = As + (half * 64 + q * 16) * 32;
    }
  } else {
#pragma unroll
    for (int q = 0; q < 4; q++) {
      int r = half * 64 + q * 16 + (ln >> 2);
      int c = (ln & 3) ^ ((r >> 1) & 3);
      gp[q] = w1t + ((size_t)e * Hh + n0 + r) * Dd + c * 8;
      ldst[q] = Bs + (half * 64 + q * 16) * 32;
    }
  }

  floatx4 zero4 = {0.f, 0.f, 0.f, 0.f};
  floatx4 acc[4][4];
#pragma unroll
  for (int i = 0; i < 4; i++)
#pragma unroll
    for (int jj = 0; jj < 4; jj++) acc[i][jj] = zero4;

  int wr = wv >> 1, wc = wv & 1;
  int lm = ln & 15, lq = ln >> 4;

  const int NK = Dd / 32;  // 32
  // prologue: tile 0 -> buffer 0
#pragma unroll
  for (int q = 0; q < 4; q++) async16(gp[q], ldst[q]);
#pragma unroll
  for (int q = 0; q < 4; q++) gp[q] += 32;

  for (int it = 0; it < NK; ++it) {
    if (it + 1 < NK) {
      int nb = (it + 1) & 1;
#pragma unroll
      for (int q = 0; q < 4; q++) async16(gp[q], ldst[q] + nb * 4096);
#pragma unroll
      for (int q = 0; q < 4; q++) gp[q] += 32;
      asm volatile("s_waitcnt vmcnt(4)" ::: "memory");
    } else {
      asm volatile("s_waitcnt vmcnt(0)" ::: "memory");
    }
    __builtin_amdgcn_s_barrier();  // tile `it` resident in LDS for all waves
    int cb = it & 1;
    const u16* Ab = As + cb * 4096;
    const u16* Bp = Bs + cb * 4096;
    short8 a[4], b[4];
#pragma unroll
    for (int i = 0; i < 4; i++) {
      int row = wr * 64 + i * 16 + lm;
      int p = lq ^ ((row >> 1) & 3);
      a[i] = *(const short8*)(Ab + row * 32 + p * 8);
    }
#pragma unroll
    for (int jj = 0; jj < 4; jj++) {
      int row = wc * 64 + jj * 16 + lm;
      int p = lq ^ ((row >> 1) & 3);
      b[jj] = *(const short8*)(Bp + row * 32 + p * 8);
    }
#pragma unroll
    for (int i = 0; i < 4; i++)
#pragma unroll
      for (int jj = 0; jj < 4; jj++)
        acc[i][jj] = __builtin_amdgcn_mfma_f32_16x16x32_bf16(a[i], b[jj], acc[i][jj], 0, 0, 0);
    asm volatile("s_waitcnt lgkmcnt(0)" ::: "memory");
    __builtin_amdgcn_s_barrier();  // all waves done reading buffer cb
  }

#pragma unroll
  for (int i = 0; i < 4; i++) {
    int rbase = wr * 64 + i * 16 + lq * 4;
#pragma unroll
    for (int r = 0; r < 4; r++) {
      int row = rbase + r;
      if (row < rows) {
        int p = lpair[row];
#pragma unroll
        for (int jj = 0; jj < 4; jj++) {
          int col = n0 + wc * 64 + jj * 16 + lm;
          float v = acc[i][jj][r] + b1[e * Hh + col];
          v = 0.5f * v * (1.0f + erff(v * 0.70710678118f));
          h[(size_t)p * Hh + col] = f2bf(v);
        }
      }
    }
  }
}

// ---------------- GEMM2: out[tok] += wt * (h @ w2[e] + b2[e]) ----------------
// grid (8, 64, E); 2-stage dbuf
__global__ __launch_bounds__(256) void gemm2(const u16* __restrict__ h,
                                             const u16* __restrict__ w2t,  // [E][D][H] bf16
                                             const float* __restrict__ b2,
                                             const int* __restrict__ counts,
                                             const int* __restrict__ tokL,
                                             const int* __restrict__ pairL,
                                             const float* __restrict__ wtL,
                                             float* __restrict__ out) {
  const int NT = 8;
  int e = blockIdx.z;
  int cnt = counts[e];
  int flat = blockIdx.x + NT * blockIdx.y;
  int x8 = flat & 7, j = flat >> 3;
  int n_t = j % NT;
  int m_t = (j / NT) * 8 + x8;
  int m0 = m_t * 128;
  if (m0 >= cnt) return;
  int rows = cnt - m0; if (rows > 128) rows = 128;
  int n0 = n_t * 128;

  __shared__ __align__(16) u16 As[2 * 128 * 32];
  __shared__ __align__(16) u16 Bs[2 * 128 * 32];
  __shared__ int ltok[128];
  __shared__ int lpair[128];
  __shared__ float lwt[128];

  int tid = threadIdx.x;
  if (tid < 128) {
    int ok = tid < rows;
    ltok[tid]  = ok ? tokL[e * Tt + m0 + tid] : 0;
    lpair[tid] = ok ? pairL[e * Tt + m0 + tid] : pairL[e * Tt + m0];
    lwt[tid]   = ok ? wtL[e * Tt + m0 + tid] : 0.f;
  }
  __syncthreads();

  int wv = tid >> 6, ln = tid & 63;
  int half = wv & 1;
  const u16* gp[4];
  u16* ldst[4];
  if (wv < 2) {
#pragma unroll
    for (int q = 0; q < 4; q++) {
      int r = half * 64 + q * 16 + (ln >> 2);
      int c = (ln & 3) ^ ((r >> 1) & 3);
      gp[q] = h + (size_t)lpair[r] * Hh + c * 8;
      ldst[q] = As + (half * 64 + q * 16) * 32;
    }
  } else {
#pragma unroll
    for (int q = 0; q < 4; q++) {
      int r = half * 64 + q * 16 + (ln >> 2);
      int c = (ln & 3) ^ ((r >> 1) & 3);
      gp[q] = w2t + ((size_t)e * Dd + n0 + r) * Hh + c * 8;
      ldst[q] = Bs + (half * 64 + q * 16) * 32;
    }
  }

  floatx4 zero4 = {0.f, 0.f, 0.f, 0.f};
  floatx4 acc[4][4];
#pragma unroll
  for (int i = 0; i < 4; i++)
#pragma unroll
    for (int jj = 0; jj < 4; jj++) acc[i][jj] = zero4;

  int wr = wv >> 1, wc = wv & 1;
  int lm = ln & 15, lq = ln >> 4;

  const int NK = Hh / 32;  // 128
#pragma unroll
  for (int q = 0; q < 4; q++) async16(gp[q], ldst[q]);
#pragma unroll
  for (int q = 0; q < 4; q++) gp[q] += 32;

  for (int it = 0; it < NK; ++it) {
    if (it + 1 < NK) {
      int nb = (it + 1) & 1;
#pragma unroll
      for (int q = 0; q < 4; q++) async16(gp[q], ldst[q] + nb * 4096);
#pragma unroll
      for (int q = 0; q < 4; q++) gp[q] += 32;
      asm volatile("s_waitcnt vmcnt(4)" ::: "memory");
    } else {
      asm volatile("s_waitcnt vmcnt(0)" ::: "memory");
    }
    __builtin_amdgcn_s_barrier();
    int cb = it & 1;
    const u16* Ab = As + cb * 4096;
    const u16* Bp = Bs + cb * 4096;
    short8 a[4], b[4];
#pragma unroll
    for (int i = 0; i < 4; i++) {
      int row = wr * 64 + i * 16 + lm;
      int p = lq ^ ((row >> 1) & 3);
      a[i] = *(const short8*)(Ab + row * 32 + p * 8);
    }
#pragma unroll
    for (int jj = 0; jj < 4; jj++) {
      int row = wc * 64 + jj * 16 + lm;
      int p = lq ^ ((row >> 1) & 3);
      b[jj] = *(const short8*)(Bp + row * 32 + p * 8);
    }
#pragma unroll
    for (int i = 0; i < 4; i++)
#pragma unroll
      for (int jj = 0; jj < 4; jj++)
        acc[i][jj] = __builtin_amdgcn_mfma_f32_16x16x32_bf16(a[i], b[jj], acc[i][jj], 0, 0, 0);
    asm volatile("s_waitcnt lgkmcnt(0)" ::: "memory");
    __builtin_amdgcn_s_barrier();
  }

#pragma unroll
  for (int i = 0; i < 4; i++) {
    int rbase = wr * 64 + i * 16 + lq * 4;
#pragma unroll
    for (int r = 0; r < 4; r++) {
      int row = rbase + r;
      if (row < rows) {
        int t = ltok[row];
        float w = lwt[row];
#pragma unroll
        for (int jj = 0; jj < 4; jj++) {
          int col = n0 + wc * 64 + jj * 16 + lm;
          float v = (acc[i][jj][r] + b2[e * Dd + col]) * w;
          atomicAdd(out + (size_t)t * Dd + col, v);
        }
      }
    }
  }
}

extern "C" void kernel_launch(void* const* d_in, const int* in_sizes, int n_in,
                              void* d_out, int out_size, void* d_ws, size_t ws_size,
                              hipStream_t stream) {
  const float* x      = (const float*)d_in[0];
  const float* gate_w = (const float*)d_in[1];
  const float* gate_b = (const float*)d_in[2];
  const float* w1     = (const float*)d_in[3];
  const float* b1     = (const float*)d_in[4];
  const float* w2     = (const float*)d_in[5];
  const float* b2     = (const float*)d_in[6];
  float* out = (float*)d_out;

  char* ws = (char*)d_ws;
  size_t off = 0;
  int* counts = (int*)(ws + off); off += 256;
  int* tokL   = (int*)(ws + off); off += (size_t)Ee * Tt * 4;
  int* pairL  = (int*)(ws + off); off += (size_t)Ee * Tt * 4;
  float* wtL  = (float*)(ws + off); off += (size_t)Ee * Tt * 4;
  u16* xb     = (u16*)(ws + off); off += (size_t)Tt * Dd * 2;
  u16* w1t    = (u16*)(ws + off); off += (size_t)Ee * Hh * Dd * 2;
  u16* w2t    = (u16*)(ws + off); off += (size_t)Ee * Dd * Hh * 2;
  u16* hbuf   = (u16*)(ws + off); off += (size_t)Tt * 2 * Hh * 2;

  hipMemsetAsync(counts, 0, 256, stream);
  hipMemsetAsync(out, 0, (size_t)Tt * Dd * 4, stream);

  cvt_x<<<(Tt * Dd) / (256 * 8), 256, 0, stream>>>(x, xb);
  tconv<<<dim3(Hh / 64, Dd / 64, Ee), 256, 0, stream>>>(w1, w1t, Dd, Hh);
  tconv<<<dim3(Dd / 64, Hh / 64, Ee), 256, 0, stream>>>(w2, w2t, Hh, Dd);
  gate_kernel<<<Tt / 4, 256, 0, stream>>>(x, gate_w, gate_b, counts, tokL, pairL, wtL);
  gemm1<<<dim3(32, 64, Ee), 256, 0, stream>>>(xb, w1t, b1, counts, tokL, pairL, hbuf);
  gemm2<<<dim3(8, 64, Ee), 256, 0, stream>>>(hbuf, w2t, b2, counts, tokL, pairL, wtL, out);
}